// Round 9
// baseline (271.621 us; speedup 1.0000x reference)
//
#include <hip/hip_runtime.h>
#include <math.h>

#define BB 16
#define NN 2048
#define FF 64
#define SS 4
#define PP 22
#define OO 42
#define FPDIM (FF + 2*PP)   // 108
#define NREG 32             // all 2048/64 d2 values kept in VGPRs per lane

__device__ __forceinline__ float readfirstlane_f32(float v) {
    // value-preserving wave-uniform broadcast (builtin is int->int; must pass bits!)
    return __uint_as_float((unsigned)__builtin_amdgcn_readfirstlane((int)__float_as_uint(v)));
}

// ---------------- Kernel 1: coords = x@W_s + b_s ; feats = x@W_f + b_f ; WoT = Wo^T ----------------
__global__ __launch_bounds__(256) void precompute_kernel(
    const float* __restrict__ x, const float* __restrict__ Ws, const float* __restrict__ bs,
    const float* __restrict__ Wf, const float* __restrict__ bf, const float* __restrict__ Wo,
    float* __restrict__ coords, float* __restrict__ feats, float* __restrict__ WoT)
{
    int row = blockIdx.x * 256 + threadIdx.x;   // 0 .. B*N-1
    if (blockIdx.x == 0) {                       // transpose Wo [108][42] -> WoT [42][108]
        for (int idx = threadIdx.x; idx < FPDIM * OO; idx += 256) {
            int k = idx / OO, o = idx - k * OO;
            WoT[o * FPDIM + k] = Wo[idx];
        }
    }
    if (row >= BB * NN) return;

    const float4* x4 = (const float4*)(x + (size_t)row * FF);
    float c0 = bs[0], c1 = bs[1], c2 = bs[2], c3 = bs[3];
    float f[PP];
    #pragma unroll
    for (int c = 0; c < PP; c++) f[c] = bf[c];

    #pragma unroll
    for (int k4 = 0; k4 < FF / 4; k4++) {
        float4 xv = x4[k4];
        float xs[4] = {xv.x, xv.y, xv.z, xv.w};
        #pragma unroll
        for (int r = 0; r < 4; r++) {
            int k = k4 * 4 + r;
            float xk = xs[r];
            c0 = fmaf(xk, Ws[k * SS + 0], c0);
            c1 = fmaf(xk, Ws[k * SS + 1], c1);
            c2 = fmaf(xk, Ws[k * SS + 2], c2);
            c3 = fmaf(xk, Ws[k * SS + 3], c3);
            #pragma unroll
            for (int c = 0; c < PP; c++) f[c] = fmaf(xk, Wf[k * PP + c], f[c]);
        }
    }
    float4* cp = (float4*)(coords + (size_t)row * SS);
    *cp = make_float4(c0, c1, c2, c3);
    float* fo = feats + (size_t)row * PP;
    #pragma unroll
    for (int c = 0; c < PP; c++) fo[c] = f[c];
}

// ---------------- Kernel 2: wave-per-query kNN + aggregate + fused output matvec/tanh ----------------
// (128,3): 3 blocks x 2 waves = 6 waves/EU -> 85-VGPR budget (R5/R7 calibration), all 32 d2
// in VGPRs. Bisection counts via ballot+popc -> v_cmp + s_bcnt on the scalar pipe.
__global__ __launch_bounds__(128, 3) void knn_out_kernel(
    const float* __restrict__ coords, const float* __restrict__ feats,
    const float* __restrict__ x, const float* __restrict__ WoT, const float* __restrict__ bo,
    const int* __restrict__ nnbr, float* __restrict__ out)
{
    const int lane = threadIdx.x & 63;
    const int w    = threadIdx.x >> 6;
    const int q    = blockIdx.x * 2 + w;       // 0..32767
    const int b    = q >> 11;
    const int i    = q & (NN - 1);

    int K = *nnbr; K = K < 2 ? 2 : (K > 64 ? 64 : K);

    __shared__ int   isel[2][64];
    __shared__ float wsel[2][64];
    __shared__ unsigned long long candk[2][64];   // (d2bits<<32)|j packed keys
    __shared__ __align__(16) float urow[2][112];  // [x | max | mean], 108 used

    const float4* cb = (const float4*)(coords + (size_t)b * NN * SS);
    float4 qv = cb[i];
    const float qx = readfirstlane_f32(qv.x);
    const float qy = readfirstlane_f32(qv.y);
    const float qz = readfirstlane_f32(qv.z);
    const float qw = readfirstlane_f32(qv.w);

    // ---- distances: all 2048 kept in 32 VGPRs/lane; track per-lane min ----
    float d2r[NREG];
    float lmin = INFINITY;
    #pragma unroll 4
    for (int r = 0; r < NREG; r++) {
        float4 c = cb[r * 64 + lane];
        float d0 = qx - c.x, d1 = qy - c.y, d2 = qz - c.z, d3 = qw - c.w;
        float v = d0 * d0 + d1 * d1 + d2 * d2 + d3 * d3;
        d2r[r] = v;
        lmin = fminf(lmin, v);
    }
    // stage x row for the epilogue (coalesced 256B per wave)
    urow[w][lane] = x[((size_t)b * NN + i) * FF + lane];
    __builtin_amdgcn_wave_barrier();

    // ---- first-probe estimator: mean of per-lane minima ~ K/N quantile ----
    float s = lmin;
    #pragma unroll
    for (int off = 1; off < 64; off <<= 1) s += __shfl_xor(s, off, 64);
    float t0 = s * (1.0f / 64.0f);

    // ---- bisection on the threshold: invariant cnt_lt(lo) < K <= cnt_lt(hi) ----
    // counts via ballot+popcll -> v_cmp + s_bcnt1_b64, wave-uniform in SGPR, no shuffle reduce
    unsigned loU = 0u, hiU = 0x7F800000u;   // [0, +inf)
    int cLo = 0, cHi = NN;
    float tPrev = t0; int cPrev = -1;
    int probes = 0;
    while (cHi - cLo > 64 && hiU - loU > 1u && probes < 34) {
        unsigned tU;
        if (probes == 0 && t0 > 0.f) {
            tU = __float_as_uint(t0);
        } else if (cPrev > 0 && probes < 8) {
            // local power law F(x) ~ x^2  ->  aim t' = t * sqrt(K/c)
            float g = tPrev * __fsqrt_rn((float)K / (float)cPrev);
            tU = __float_as_uint(g);
        } else if (cPrev == 0 && probes < 8) {
            tU = __float_as_uint(tPrev * 4.0f);
        } else {
            tU = loU + ((hiU - loU) >> 1);
        }
        if (tU <= loU || tU >= hiU) tU = loU + ((hiU - loU) >> 1);   // guaranteed shrink
        float t = __uint_as_float(tU);
        int c = 0;
        #pragma unroll
        for (int r = 0; r < NREG; r++) c += (int)__popcll(__ballot(d2r[r] < t));
        if (c >= K) { hiU = tU; cHi = c; } else { loU = tU; cLo = c; }
        tPrev = t; cPrev = c;
        probes++;
    }

    const float lo = __uint_as_float(loU);
    const float hi = __uint_as_float(hiU);
    const int  need = K - cLo;              // in [1, K]; window holds >= need values

    // ---- collect, two-phase lane-local: count -> packed wave scan -> sequential writes ----
    int c1 = 0, c2 = 0;
    #pragma unroll
    for (int r = 0; r < NREG; r++) {
        float v = d2r[r];
        int j = r * 64 + lane;
        c1 += ((v < lo) & (j != i)) ? 1 : 0;
        c2 += ((v >= lo) & (v < hi)) ? 1 : 0;
    }
    int pk = c1 | (c2 << 16);
    int inc = pk;
    #pragma unroll
    for (int off = 1; off < 64; off <<= 1) {
        int t2 = __shfl_up(inc, off, 64);
        if (lane >= off) inc += t2;
    }
    int excl = inc - pk;
    int tot  = __shfl(inc, 63, 64);
    int b1 = excl & 0xFFFF;            // per-lane write base, below-window
    int b2 = excl >> 16;               // per-lane write base, candidates
    const int nbelow = tot & 0xFFFF;   // <= K-1
    int ecand = tot >> 16; if (ecand > 64) ecand = 64;
    #pragma unroll
    for (int r = 0; r < NREG; r++) {
        float v = d2r[r];
        int j = r * 64 + lane;
        if ((v < lo) & (j != i)) { isel[w][b1] = j; wsel[w][b1] = v; b1++; }
        else if ((v >= lo) & (v < hi)) { if (b2 < 64) candk[w][b2] = ((unsigned long long)__float_as_uint(v) << 32) | (unsigned)j; b2++; }
    }
    __builtin_amdgcn_wave_barrier();

    // ---- rank candidates by (value, index); append `need` smallest, skipping self ----
    int nsel;
    {
        unsigned long long mykey = ~0ull;
        if (lane < ecand) mykey = candk[w][lane];
        int mr = 0;
        for (int u = 0; u < ecand; u++) {        // ds_read_b64 broadcast, conflict-free
            unsigned long long k2 = candk[w][u];
            mr += (k2 < mykey) ? 1 : 0;
        }
        int mj = (int)(mykey & 0xFFFFFFFFull);
        bool ps = (lane < ecand) & (mr < need) & (mj != i);
        unsigned long long ms = __ballot(ps);
        if (ps) {
            int slot = nbelow + __popcll(ms & ((1ull << lane) - 1ull));
            if (slot < 64) { isel[w][slot] = mj; wsel[w][slot] = __uint_as_float((unsigned)(mykey >> 32)); }
        }
        nsel = nbelow + __popcll(ms);
        if (nsel > 64) nsel = 64;                // expect K-1 = 39
    }
    __builtin_amdgcn_wave_barrier();
    if (lane < nsel) wsel[w][lane] = __expf(-wsel[w][lane]);
    __builtin_amdgcn_wave_barrier();

    // ---- weighted max / mean: lanes 0-21 do even m, lanes 32-53 odd m ----
    const float* fb = feats + (size_t)b * NN * PP;
    int g = lane >> 5, c = lane & 31;
    float mx = -INFINITY, sm = 0.f;
    if (c < PP) {
        for (int m = g; m < nsel; m += 2) {
            int j = isel[w][m]; float wt = wsel[w][m];
            float f = fb[(size_t)j * PP + c];
            float wf = wt * f;
            mx = fmaxf(mx, wf); sm += wf;
        }
    }
    float mx2 = __shfl_xor(mx, 32, 64);
    float sm2 = __shfl_xor(sm, 32, 64);
    mx = fmaxf(mx, mx2); sm += sm2;
    if (g == 0 && c < PP) {
        urow[w][FF + c]      = mx;
        urow[w][FF + PP + c] = sm / (float)(K - 1);
    }
    __builtin_amdgcn_wave_barrier();

    // ---- fused epilogue: out[q][o] = tanh(urow . WoT[o] + bo[o]), lanes 0-41 ----
    if (lane < OO) {
        float acc = bo[lane];
        const float4* wr = (const float4*)(WoT + (size_t)lane * FPDIM);
        #pragma unroll 9
        for (int k4 = 0; k4 < FPDIM / 4; k4++) {
            float4 u  = *((const float4*)&urow[w][k4 * 4]);   // ds_read_b128 broadcast
            float4 ww = wr[k4];                               // global float4, L2-resident
            acc = fmaf(u.x, ww.x, acc);
            acc = fmaf(u.y, ww.y, acc);
            acc = fmaf(u.z, ww.z, acc);
            acc = fmaf(u.w, ww.w, acc);
        }
        float a = acc < -12.f ? -12.f : (acc > 12.f ? 12.f : acc);
        float e2 = __expf(2.f * a);
        out[(size_t)q * OO + lane] = (e2 - 1.f) / (e2 + 1.f);
    }
}

extern "C" void kernel_launch(void* const* d_in, const int* in_sizes, int n_in,
                              void* d_out, int out_size, void* d_ws, size_t ws_size,
                              hipStream_t stream) {
    const float* x  = (const float*)d_in[0];
    const float* Ws = (const float*)d_in[1];
    const float* bs = (const float*)d_in[2];
    const float* Wf = (const float*)d_in[3];
    const float* bf = (const float*)d_in[4];
    const float* Wo = (const float*)d_in[5];
    const float* bo = (const float*)d_in[6];
    const int*   nn = (const int*)d_in[7];
    float* out = (float*)d_out;

    float* coords = (float*)d_ws;                              // 16*2048*4  = 512 KB
    float* feats  = coords + (size_t)BB * NN * SS;             // 16*2048*22 = 2.75 MB
    float* WoT    = feats  + (size_t)BB * NN * PP;             // 42*108 floats = 18 KB

    precompute_kernel<<<(BB * NN) / 256, 256, 0, stream>>>(x, Ws, bs, Wf, bf, Wo, coords, feats, WoT);
    knn_out_kernel<<<(BB * NN) / 2, 128, 0, stream>>>(coords, feats, x, WoT, bo, nn, out);
}

// Round 10
// 206.664 us; speedup vs baseline: 1.3143x; 1.3143x over previous
//
#include <hip/hip_runtime.h>
#include <math.h>

#define BB 16
#define NN 2048
#define FF 64
#define SS 4
#define PP 22
#define OO 42
#define FPDIM (FF + 2*PP)   // 108
#define NREG 32             // all 2048/64 d2 values kept in VGPRs per lane (R9: fits in 56 VGPRs)

__device__ __forceinline__ float readfirstlane_f32(float v) {
    // value-preserving wave-uniform broadcast (builtin is int->int; must pass bits!)
    return __uint_as_float((unsigned)__builtin_amdgcn_readfirstlane((int)__float_as_uint(v)));
}

// ---------------- Kernel 1: coords = x@W_s + b_s ; feats = x@W_f + b_f ; WoT = Wo^T ----------------
__global__ __launch_bounds__(256) void precompute_kernel(
    const float* __restrict__ x, const float* __restrict__ Ws, const float* __restrict__ bs,
    const float* __restrict__ Wf, const float* __restrict__ bf, const float* __restrict__ Wo,
    float* __restrict__ coords, float* __restrict__ feats, float* __restrict__ WoT)
{
    int row = blockIdx.x * 256 + threadIdx.x;   // 0 .. B*N-1
    if (blockIdx.x == 0) {                       // transpose Wo [108][42] -> WoT [42][108]
        for (int idx = threadIdx.x; idx < FPDIM * OO; idx += 256) {
            int k = idx / OO, o = idx - k * OO;
            WoT[o * FPDIM + k] = Wo[idx];
        }
    }
    if (row >= BB * NN) return;

    const float4* x4 = (const float4*)(x + (size_t)row * FF);
    float c0 = bs[0], c1 = bs[1], c2 = bs[2], c3 = bs[3];
    float f[PP];
    #pragma unroll
    for (int c = 0; c < PP; c++) f[c] = bf[c];

    #pragma unroll
    for (int k4 = 0; k4 < FF / 4; k4++) {
        float4 xv = x4[k4];
        float xs[4] = {xv.x, xv.y, xv.z, xv.w};
        #pragma unroll
        for (int r = 0; r < 4; r++) {
            int k = k4 * 4 + r;
            float xk = xs[r];
            c0 = fmaf(xk, Ws[k * SS + 0], c0);
            c1 = fmaf(xk, Ws[k * SS + 1], c1);
            c2 = fmaf(xk, Ws[k * SS + 2], c2);
            c3 = fmaf(xk, Ws[k * SS + 3], c3);
            #pragma unroll
            for (int c = 0; c < PP; c++) f[c] = fmaf(xk, Wf[k * PP + c], f[c]);
        }
    }
    float4* cp = (float4*)(coords + (size_t)row * SS);
    *cp = make_float4(c0, c1, c2, c3);
    float* fo = feats + (size_t)row * PP;
    #pragma unroll
    for (int c = 0; c < PP; c++) fo[c] = f[c];
}

// ---------------- Kernel 2: wave-per-query kNN + aggregate + fused output matvec/tanh ----------------
// (128,4): 4 blocks x 2 waves = 8 waves/EU -> 64-VGPR budget. All 32 d2 in VGPRs (R9: 56 used).
// VALU counting (no SALU-hazard ballot); per-lane counts stashed at lo/hi updates so the
// collect phase needs no recount pass.
__global__ __launch_bounds__(128, 4) void knn_out_kernel(
    const float* __restrict__ coords, const float* __restrict__ feats,
    const float* __restrict__ x, const float* __restrict__ WoT, const float* __restrict__ bo,
    const int* __restrict__ nnbr, float* __restrict__ out)
{
    const int lane = threadIdx.x & 63;
    const int w    = threadIdx.x >> 6;
    const int q    = blockIdx.x * 2 + w;       // 0..32767
    const int b    = q >> 11;
    const int i    = q & (NN - 1);

    int K = *nnbr; K = K < 2 ? 2 : (K > 64 ? 64 : K);

    __shared__ int   isel[2][64];
    __shared__ float wsel[2][64];
    __shared__ unsigned long long candk[2][64];   // (d2bits<<32)|j packed keys
    __shared__ __align__(16) float urow[2][112];  // [x | max | mean], 108 used

    const float4* cb = (const float4*)(coords + (size_t)b * NN * SS);
    float4 qv = cb[i];
    const float qx = readfirstlane_f32(qv.x);
    const float qy = readfirstlane_f32(qv.y);
    const float qz = readfirstlane_f32(qv.z);
    const float qw = readfirstlane_f32(qv.w);

    // ---- distances: all 2048 kept in 32 VGPRs/lane; track per-lane min ----
    float d2r[NREG];
    float lmin = INFINITY;
    #pragma unroll 4
    for (int r = 0; r < NREG; r++) {
        float4 c = cb[r * 64 + lane];
        float d0 = qx - c.x, d1 = qy - c.y, d2 = qz - c.z, d3 = qw - c.w;
        float v = d0 * d0 + d1 * d1 + d2 * d2 + d3 * d3;
        d2r[r] = v;
        lmin = fminf(lmin, v);
    }
    // stage x row for the epilogue (coalesced 256B per wave)
    urow[w][lane] = x[((size_t)b * NN + i) * FF + lane];
    __builtin_amdgcn_wave_barrier();

    // ---- first-probe estimator: mean of per-lane minima ~ K/N quantile ----
    float s = lmin;
    #pragma unroll
    for (int off = 1; off < 64; off <<= 1) s += __shfl_xor(s, off, 64);
    float t0 = s * (1.0f / 64.0f);

    // ---- bisection: invariant cnt_lt(lo) < K <= cnt_lt(hi); stash per-lane counts ----
    unsigned loU = 0u, hiU = 0x7F800000u;   // [0, +inf)
    int cLo = 0, cHi = NN;
    int laneLo = 0, laneHi = NREG;          // per-lane counts at loU / hiU
    float tPrev = t0; int cPrev = -1;
    int probes = 0;
    while (cHi - cLo > 64 && hiU - loU > 1u && probes < 34) {
        unsigned tU;
        if (probes == 0 && t0 > 0.f) {
            tU = __float_as_uint(t0);
        } else if (cPrev > 0 && probes < 8) {
            // local power law F(x) ~ x^2  ->  aim t' = t * sqrt(K/c)
            float g = tPrev * __fsqrt_rn((float)K / (float)cPrev);
            tU = __float_as_uint(g);
        } else if (cPrev == 0 && probes < 8) {
            tU = __float_as_uint(tPrev * 4.0f);
        } else {
            tU = loU + ((hiU - loU) >> 1);
        }
        if (tU <= loU || tU >= hiU) tU = loU + ((hiU - loU) >> 1);   // guaranteed shrink
        float t = __uint_as_float(tU);
        int cl = 0;
        #pragma unroll
        for (int r = 0; r < NREG; r++) cl += (d2r[r] < t) ? 1 : 0;
        int c = cl;
        #pragma unroll
        for (int off = 1; off < 64; off <<= 1) c += __shfl_xor(c, off, 64);
        if (c >= K) { hiU = tU; cHi = c; laneHi = cl; }
        else        { loU = tU; cLo = c; laneLo = cl; }
        tPrev = t; cPrev = c;
        probes++;
    }

    const float lo = __uint_as_float(loU);
    const float hi = __uint_as_float(hiU);
    const int  need = K - cLo;              // in [1, K]; window holds >= need values

    // ---- collect: counts already known per lane (laneLo/laneHi); scan -> sequential writes ----
    int c1 = laneLo;                        // # of my elems with v < lo, minus self if below
    int c2 = laneHi - laneLo;               // # of my elems in [lo, hi)
    if (lane == (i & 63) && loU > 0u) c1 -= 1;   // self d2=0 < lo counted in laneLo
    int pk = c1 | (c2 << 16);
    int inc = pk;
    #pragma unroll
    for (int off = 1; off < 64; off <<= 1) {
        int t2 = __shfl_up(inc, off, 64);
        if (lane >= off) inc += t2;
    }
    int excl = inc - pk;
    int tot  = __shfl(inc, 63, 64);
    int b1 = excl & 0xFFFF;            // per-lane write base, below-window
    int b2 = excl >> 16;               // per-lane write base, candidates
    const int nbelow = tot & 0xFFFF;   // <= K-1
    int ecand = tot >> 16; if (ecand > 64) ecand = 64;
    #pragma unroll
    for (int r = 0; r < NREG; r++) {
        float v = d2r[r];
        int j = r * 64 + lane;
        if ((v < lo) & (j != i)) { isel[w][b1] = j; wsel[w][b1] = v; b1++; }
        else if ((v >= lo) & (v < hi)) { if (b2 < 64) candk[w][b2] = ((unsigned long long)__float_as_uint(v) << 32) | (unsigned)j; b2++; }
    }
    __builtin_amdgcn_wave_barrier();

    // ---- rank candidates by (value, index); append `need` smallest, skipping self ----
    int nsel;
    {
        unsigned long long mykey = ~0ull;
        if (lane < ecand) mykey = candk[w][lane];
        int mr = 0;
        for (int u = 0; u < ecand; u++) {        // ds_read_b64 broadcast, conflict-free
            unsigned long long k2 = candk[w][u];
            mr += (k2 < mykey) ? 1 : 0;
        }
        int mj = (int)(mykey & 0xFFFFFFFFull);
        bool ps = (lane < ecand) & (mr < need) & (mj != i);
        unsigned long long ms = __ballot(ps);
        if (ps) {
            int slot = nbelow + __popcll(ms & ((1ull << lane) - 1ull));
            if (slot < 64) { isel[w][slot] = mj; wsel[w][slot] = __uint_as_float((unsigned)(mykey >> 32)); }
        }
        nsel = nbelow + __popcll(ms);
        if (nsel > 64) nsel = 64;                // expect K-1 = 39
    }
    __builtin_amdgcn_wave_barrier();
    if (lane < nsel) wsel[w][lane] = __expf(-wsel[w][lane]);
    __builtin_amdgcn_wave_barrier();

    // ---- weighted max / mean: lanes 0-21 do even m, lanes 32-53 odd m ----
    const float* fb = feats + (size_t)b * NN * PP;
    int g = lane >> 5, c = lane & 31;
    float mx = -INFINITY, sm = 0.f;
    if (c < PP) {
        #pragma unroll 4
        for (int m = g; m < nsel; m += 2) {
            int j = isel[w][m]; float wt = wsel[w][m];
            float f = fb[(size_t)j * PP + c];
            float wf = wt * f;
            mx = fmaxf(mx, wf); sm += wf;
        }
    }
    float mx2 = __shfl_xor(mx, 32, 64);
    float sm2 = __shfl_xor(sm, 32, 64);
    mx = fmaxf(mx, mx2); sm += sm2;
    if (g == 0 && c < PP) {
        urow[w][FF + c]      = mx;
        urow[w][FF + PP + c] = sm / (float)(K - 1);
    }
    __builtin_amdgcn_wave_barrier();

    // ---- fused epilogue: out[q][o] = tanh(urow . WoT[o] + bo[o]), lanes 0-41 ----
    if (lane < OO) {
        float acc = bo[lane];
        const float4* wr = (const float4*)(WoT + (size_t)lane * FPDIM);
        #pragma unroll 9
        for (int k4 = 0; k4 < FPDIM / 4; k4++) {
            float4 u  = *((const float4*)&urow[w][k4 * 4]);   // ds_read_b128 broadcast
            float4 ww = wr[k4];                               // global float4, L2-resident
            acc = fmaf(u.x, ww.x, acc);
            acc = fmaf(u.y, ww.y, acc);
            acc = fmaf(u.z, ww.z, acc);
            acc = fmaf(u.w, ww.w, acc);
        }
        float a = acc < -12.f ? -12.f : (acc > 12.f ? 12.f : acc);
        float e2 = __expf(2.f * a);
        out[(size_t)q * OO + lane] = (e2 - 1.f) / (e2 + 1.f);
    }
}

extern "C" void kernel_launch(void* const* d_in, const int* in_sizes, int n_in,
                              void* d_out, int out_size, void* d_ws, size_t ws_size,
                              hipStream_t stream) {
    const float* x  = (const float*)d_in[0];
    const float* Ws = (const float*)d_in[1];
    const float* bs = (const float*)d_in[2];
    const float* Wf = (const float*)d_in[3];
    const float* bf = (const float*)d_in[4];
    const float* Wo = (const float*)d_in[5];
    const float* bo = (const float*)d_in[6];
    const int*   nn = (const int*)d_in[7];
    float* out = (float*)d_out;

    float* coords = (float*)d_ws;                              // 16*2048*4  = 512 KB
    float* feats  = coords + (size_t)BB * NN * SS;             // 16*2048*22 = 2.75 MB
    float* WoT    = feats  + (size_t)BB * NN * PP;             // 42*108 floats = 18 KB

    precompute_kernel<<<(BB * NN) / 256, 256, 0, stream>>>(x, Ws, bs, Wf, bf, Wo, coords, feats, WoT);
    knn_out_kernel<<<(BB * NN) / 2, 128, 0, stream>>>(coords, feats, x, WoT, bo, nn, out);
}

// Round 11
// 191.339 us; speedup vs baseline: 1.4196x; 1.0801x over previous
//
#include <hip/hip_runtime.h>
#include <math.h>

#define BB 16
#define NN 2048
#define FF 64
#define SS 4
#define PP 22
#define OO 42
#define FPDIM (FF + 2*PP)   // 108
#define NREG 32             // all 2048/64 d2 values kept in VGPRs per lane

__device__ __forceinline__ float readfirstlane_f32(float v) {
    // value-preserving wave-uniform broadcast (builtin is int->int; must pass bits!)
    return __uint_as_float((unsigned)__builtin_amdgcn_readfirstlane((int)__float_as_uint(v)));
}

// canonical GCN wave64 sum: row_shr 1/2/4/8 (bound_ctrl -> OOB reads 0), then
// row_bcast:15 into rows 1,3 and row_bcast:31 into rows 2,3; total lands in lane 63.
// x += update_dpp(0, x, ...): masked/OOB lanes of the temp are 0, x itself preserved.
__device__ __forceinline__ int wave_sum_dpp(int x) {
    x += __builtin_amdgcn_update_dpp(0, x, 0x111, 0xf, 0xf, true);  // row_shr:1
    x += __builtin_amdgcn_update_dpp(0, x, 0x112, 0xf, 0xf, true);  // row_shr:2
    x += __builtin_amdgcn_update_dpp(0, x, 0x114, 0xf, 0xf, true);  // row_shr:4
    x += __builtin_amdgcn_update_dpp(0, x, 0x118, 0xf, 0xf, true);  // row_shr:8
    x += __builtin_amdgcn_update_dpp(0, x, 0x142, 0xa, 0xf, true);  // row_bcast:15 -> rows 1,3
    x += __builtin_amdgcn_update_dpp(0, x, 0x143, 0xc, 0xf, true);  // row_bcast:31 -> rows 2,3
    return __builtin_amdgcn_readlane(x, 63);
}

// ---------------- Kernel 1: coords = x@W_s + b_s ; feats = x@W_f + b_f ----------------
__global__ __launch_bounds__(256) void precompute_kernel(
    const float* __restrict__ x, const float* __restrict__ Ws, const float* __restrict__ bs,
    const float* __restrict__ Wf, const float* __restrict__ bf,
    float* __restrict__ coords, float* __restrict__ feats)
{
    int row = blockIdx.x * 256 + threadIdx.x;   // 0 .. B*N-1
    if (row >= BB * NN) return;

    const float4* x4 = (const float4*)(x + (size_t)row * FF);
    float c0 = bs[0], c1 = bs[1], c2 = bs[2], c3 = bs[3];
    float f[PP];
    #pragma unroll
    for (int c = 0; c < PP; c++) f[c] = bf[c];

    #pragma unroll
    for (int k4 = 0; k4 < FF / 4; k4++) {
        float4 xv = x4[k4];
        float xs[4] = {xv.x, xv.y, xv.z, xv.w};
        #pragma unroll
        for (int r = 0; r < 4; r++) {
            int k = k4 * 4 + r;
            float xk = xs[r];
            c0 = fmaf(xk, Ws[k * SS + 0], c0);
            c1 = fmaf(xk, Ws[k * SS + 1], c1);
            c2 = fmaf(xk, Ws[k * SS + 2], c2);
            c3 = fmaf(xk, Ws[k * SS + 3], c3);
            #pragma unroll
            for (int c = 0; c < PP; c++) f[c] = fmaf(xk, Wf[k * PP + c], f[c]);
        }
    }
    float4* cp = (float4*)(coords + (size_t)row * SS);
    *cp = make_float4(c0, c1, c2, c3);
    float* fo = feats + (size_t)row * PP;
    #pragma unroll
    for (int c = 0; c < PP; c++) fo[c] = f[c];
}

// ---------------- Kernel 2: wave-per-query kNN + aggregate + fused output matvec/tanh ----------------
// (128,4) -> 8 waves/EU budget. All 32 d2 in VGPRs (R10: 36 VGPRs used). Dual-threshold
// bisection (2 counts per round-trip, packed) with DPP wave-sum. Epilogue reads original
// Wo layout: lane o loads Wo[k*42+o] -> coalesced.
__global__ __launch_bounds__(128, 4) void knn_out_kernel(
    const float* __restrict__ coords, const float* __restrict__ feats,
    const float* __restrict__ x, const float* __restrict__ Wo, const float* __restrict__ bo,
    const int* __restrict__ nnbr, float* __restrict__ out)
{
    const int lane = threadIdx.x & 63;
    const int w    = threadIdx.x >> 6;
    const int q    = blockIdx.x * 2 + w;       // 0..32767
    const int b    = q >> 11;
    const int i    = q & (NN - 1);

    int K = *nnbr; K = K < 2 ? 2 : (K > 64 ? 64 : K);

    __shared__ int   isel[2][64];
    __shared__ float wsel[2][64];
    __shared__ unsigned long long candk[2][64];   // (d2bits<<32)|j packed keys
    __shared__ __align__(16) float urow[2][112];  // [x | max | mean], 108 used

    const float4* cb = (const float4*)(coords + (size_t)b * NN * SS);
    float4 qv = cb[i];
    const float qx = readfirstlane_f32(qv.x);
    const float qy = readfirstlane_f32(qv.y);
    const float qz = readfirstlane_f32(qv.z);
    const float qw = readfirstlane_f32(qv.w);

    // ---- distances: all 2048 kept in 32 VGPRs/lane; track per-lane min ----
    float d2r[NREG];
    float lmin = INFINITY;
    #pragma unroll 4
    for (int r = 0; r < NREG; r++) {
        float4 c = cb[r * 64 + lane];
        float d0 = qx - c.x, d1 = qy - c.y, d2 = qz - c.z, d3 = qw - c.w;
        float v = d0 * d0 + d1 * d1 + d2 * d2 + d3 * d3;
        d2r[r] = v;
        lmin = fminf(lmin, v);
    }
    // stage x row for the epilogue (coalesced 256B per wave)
    urow[w][lane] = x[((size_t)b * NN + i) * FF + lane];
    __builtin_amdgcn_wave_barrier();

    // ---- first-probe estimator: mean of per-lane minima ~ K/N quantile ----
    float s = lmin;
    #pragma unroll
    for (int off = 1; off < 64; off <<= 1) s += __shfl_xor(s, off, 64);
    float t0 = s * (1.0f / 64.0f);

    // ---- dual-threshold bisection: invariant cnt_lt(lo) < K <= cnt_lt(hi) ----
    unsigned loU = 0u, hiU = 0x7F800000u;   // [0, +inf)
    int cLo = 0, cHi = NN;
    int laneLo = 0, laneHi = NREG;          // per-lane counts at loU / hiU
    float tPrev = t0; int cPrev = -1;
    int probes = 0;
    while (cHi - cLo > 64 && hiU - loU > 1u && probes < 20) {
        unsigned tAU = 0u, tBU = 0u;
        bool fell = false;
        if (probes == 0) {
            if (t0 > 0.f) { tAU = __float_as_uint(t0 * 0.80f); tBU = __float_as_uint(t0 * 1.30f); }
            else fell = true;
        } else if (cPrev > 0) {
            float g = tPrev * __fsqrt_rn((float)K / (float)cPrev);
            tAU = __float_as_uint(g * 0.88f); tBU = __float_as_uint(g * 1.18f);
        } else if (cPrev == 0) {
            tAU = __float_as_uint(tPrev * 3.0f); tBU = __float_as_uint(tPrev * 9.0f);
        } else fell = true;
        unsigned span = hiU - loU;
        if (fell || !(tAU > loU && tAU < hiU)) tAU = loU + span / 3u;
        if (tAU <= loU) tAU = loU + 1u;
        if (tAU >= hiU) tAU = hiU - 1u;
        if (fell || !(tBU >= tAU && tBU < hiU)) tBU = tAU + (hiU - tAU) / 2u;
        if (tBU < tAU) tBU = tAU;
        if (tBU >= hiU) tBU = hiU - 1u;

        float tA = __uint_as_float(tAU), tB = __uint_as_float(tBU);
        int clA = 0, clB = 0;
        #pragma unroll
        for (int r = 0; r < NREG; r++) {
            clA += (d2r[r] < tA) ? 1 : 0;
            clB += (d2r[r] < tB) ? 1 : 0;
        }
        int tot = wave_sum_dpp(clA | (clB << 16));   // sums fit 16 bits each (<= 2048)
        int cA = tot & 0xFFFF, cB = tot >> 16;

        if (cA >= K) { hiU = tAU; cHi = cA; laneHi = clA; }
        else {
            loU = tAU; cLo = cA; laneLo = clA;
            if (cB >= K) { hiU = tBU; cHi = cB; laneHi = clB; }
            else         { loU = tBU; cLo = cB; laneLo = clB; }
        }
        // anchor for the power-law guess: nonzero count closest to K
        int dA = cA > K ? cA - K : K - cA;
        int dB = cB > K ? cB - K : K - cB;
        if (cA > 0 && dA <= dB) { tPrev = tA; cPrev = cA; }
        else                    { tPrev = tB; cPrev = cB; }
        probes++;
    }

    const float lo = __uint_as_float(loU);
    const float hi = __uint_as_float(hiU);
    const int  need = K - cLo;              // in [1, K]; window holds >= need values

    // ---- collect: counts already known per lane (laneLo/laneHi); scan -> sequential writes ----
    int c1 = laneLo;                        // # of my elems with v < lo, minus self if below
    int c2 = laneHi - laneLo;               // # of my elems in [lo, hi)
    if (lane == (i & 63) && loU > 0u) c1 -= 1;   // self d2=0 < lo counted in laneLo
    int pk = c1 | (c2 << 16);
    int inc = pk;
    #pragma unroll
    for (int off = 1; off < 64; off <<= 1) {
        int t2 = __shfl_up(inc, off, 64);
        if (lane >= off) inc += t2;
    }
    int excl = inc - pk;
    int tot  = __shfl(inc, 63, 64);
    int b1 = excl & 0xFFFF;            // per-lane write base, below-window
    int b2 = excl >> 16;               // per-lane write base, candidates
    const int nbelow = tot & 0xFFFF;   // <= K-1
    int ecand = tot >> 16; if (ecand > 64) ecand = 64;
    #pragma unroll
    for (int r = 0; r < NREG; r++) {
        float v = d2r[r];
        int j = r * 64 + lane;
        if ((v < lo) & (j != i)) { isel[w][b1] = j; wsel[w][b1] = v; b1++; }
        else if ((v >= lo) & (v < hi)) { if (b2 < 64) candk[w][b2] = ((unsigned long long)__float_as_uint(v) << 32) | (unsigned)j; b2++; }
    }
    __builtin_amdgcn_wave_barrier();

    // ---- rank candidates by (value, index); append `need` smallest, skipping self ----
    int nsel;
    {
        unsigned long long mykey = ~0ull;
        if (lane < ecand) mykey = candk[w][lane];
        int mr = 0;
        for (int u = 0; u < ecand; u++) {        // ds_read_b64 broadcast, conflict-free
            unsigned long long k2 = candk[w][u];
            mr += (k2 < mykey) ? 1 : 0;
        }
        int mj = (int)(mykey & 0xFFFFFFFFull);
        bool ps = (lane < ecand) & (mr < need) & (mj != i);
        unsigned long long ms = __ballot(ps);
        if (ps) {
            int slot = nbelow + __popcll(ms & ((1ull << lane) - 1ull));
            if (slot < 64) { isel[w][slot] = mj; wsel[w][slot] = __uint_as_float((unsigned)(mykey >> 32)); }
        }
        nsel = nbelow + __popcll(ms);
        if (nsel > 64) nsel = 64;                // expect K-1 = 39
    }
    __builtin_amdgcn_wave_barrier();
    if (lane < nsel) wsel[w][lane] = __expf(-wsel[w][lane]);
    __builtin_amdgcn_wave_barrier();

    // ---- weighted max / mean: lanes 0-21 do even m, lanes 32-53 odd m ----
    const float* fb = feats + (size_t)b * NN * PP;
    int g = lane >> 5, c = lane & 31;
    float mx = -INFINITY, sm = 0.f;
    if (c < PP) {
        #pragma unroll 4
        for (int m = g; m < nsel; m += 2) {
            int j = isel[w][m]; float wt = wsel[w][m];
            float f = fb[(size_t)j * PP + c];
            float wf = wt * f;
            mx = fmaxf(mx, wf); sm += wf;
        }
    }
    float mx2 = __shfl_xor(mx, 32, 64);
    float sm2 = __shfl_xor(sm, 32, 64);
    mx = fmaxf(mx, mx2); sm += sm2;
    if (g == 0 && c < PP) {
        urow[w][FF + c]      = mx;
        urow[w][FF + PP + c] = sm / (float)(K - 1);
    }
    __builtin_amdgcn_wave_barrier();

    // ---- fused epilogue: out[q][o] = tanh(urow . Wo[:,o] + bo[o]), lanes 0-41 ----
    // original Wo layout [108][42]: lane o reads Wo[k*42+o] -> coalesced across lanes
    if (lane < OO) {
        float acc = bo[lane];
        const float* wo = Wo + lane;
        #pragma unroll
        for (int k4 = 0; k4 < FPDIM / 4; k4++) {
            float4 u = *((const float4*)&urow[w][k4 * 4]);   // ds_read_b128 broadcast
            acc = fmaf(u.x, wo[(k4 * 4 + 0) * OO], acc);
            acc = fmaf(u.y, wo[(k4 * 4 + 1) * OO], acc);
            acc = fmaf(u.z, wo[(k4 * 4 + 2) * OO], acc);
            acc = fmaf(u.w, wo[(k4 * 4 + 3) * OO], acc);
        }
        float a = acc < -12.f ? -12.f : (acc > 12.f ? 12.f : acc);
        float e2 = __expf(2.f * a);
        out[(size_t)q * OO + lane] = (e2 - 1.f) / (e2 + 1.f);
    }
}

extern "C" void kernel_launch(void* const* d_in, const int* in_sizes, int n_in,
                              void* d_out, int out_size, void* d_ws, size_t ws_size,
                              hipStream_t stream) {
    const float* x  = (const float*)d_in[0];
    const float* Ws = (const float*)d_in[1];
    const float* bs = (const float*)d_in[2];
    const float* Wf = (const float*)d_in[3];
    const float* bf = (const float*)d_in[4];
    const float* Wo = (const float*)d_in[5];
    const float* bo = (const float*)d_in[6];
    const int*   nn = (const int*)d_in[7];
    float* out = (float*)d_out;

    float* coords = (float*)d_ws;                              // 16*2048*4  = 512 KB
    float* feats  = coords + (size_t)BB * NN * SS;             // 16*2048*22 = 2.75 MB

    precompute_kernel<<<(BB * NN) / 256, 256, 0, stream>>>(x, Ws, bs, Wf, bf, coords, feats);
    knn_out_kernel<<<(BB * NN) / 2, 128, 0, stream>>>(coords, feats, x, Wo, bo, nn, out);
}

// Round 12
// 186.029 us; speedup vs baseline: 1.4601x; 1.0285x over previous
//
#include <hip/hip_runtime.h>
#include <math.h>

#define BB 16
#define NN 2048
#define FF 64
#define SS 4
#define PP 22
#define OO 42
#define FPDIM (FF + 2*PP)   // 108
#define NREG 32             // all 2048/64 d2 values kept in VGPRs per lane

__device__ __forceinline__ float readfirstlane_f32(float v) {
    // value-preserving wave-uniform broadcast (builtin is int->int; must pass bits!)
    return __uint_as_float((unsigned)__builtin_amdgcn_readfirstlane((int)__float_as_uint(v)));
}

// canonical GCN wave64 inclusive scan via DPP: row_shr 1/2/4/8 (bound_ctrl -> OOB reads 0),
// then row_bcast:15 into rows 1,3 and row_bcast:31 into rows 2,3.
// Each lane ends with its inclusive prefix; lane 63 holds the wave total. [R11-validated chain]
__device__ __forceinline__ int wave_scan_dpp(int x) {
    x += __builtin_amdgcn_update_dpp(0, x, 0x111, 0xf, 0xf, true);  // row_shr:1
    x += __builtin_amdgcn_update_dpp(0, x, 0x112, 0xf, 0xf, true);  // row_shr:2
    x += __builtin_amdgcn_update_dpp(0, x, 0x114, 0xf, 0xf, true);  // row_shr:4
    x += __builtin_amdgcn_update_dpp(0, x, 0x118, 0xf, 0xf, true);  // row_shr:8
    x += __builtin_amdgcn_update_dpp(0, x, 0x142, 0xa, 0xf, true);  // row_bcast:15 -> rows 1,3
    x += __builtin_amdgcn_update_dpp(0, x, 0x143, 0xc, 0xf, true);  // row_bcast:31 -> rows 2,3
    return x;
}
__device__ __forceinline__ int wave_sum_dpp(int x) {
    return __builtin_amdgcn_readlane(wave_scan_dpp(x), 63);
}
// float wave sum: same chain, adds in float domain (0-bits = 0.0f additive identity)
__device__ __forceinline__ float wave_fsum_dpp(float x) {
    float t;
    t = __uint_as_float((unsigned)__builtin_amdgcn_update_dpp(0, (int)__float_as_uint(x), 0x111, 0xf, 0xf, true)); x += t;
    t = __uint_as_float((unsigned)__builtin_amdgcn_update_dpp(0, (int)__float_as_uint(x), 0x112, 0xf, 0xf, true)); x += t;
    t = __uint_as_float((unsigned)__builtin_amdgcn_update_dpp(0, (int)__float_as_uint(x), 0x114, 0xf, 0xf, true)); x += t;
    t = __uint_as_float((unsigned)__builtin_amdgcn_update_dpp(0, (int)__float_as_uint(x), 0x118, 0xf, 0xf, true)); x += t;
    t = __uint_as_float((unsigned)__builtin_amdgcn_update_dpp(0, (int)__float_as_uint(x), 0x142, 0xa, 0xf, true)); x += t;
    t = __uint_as_float((unsigned)__builtin_amdgcn_update_dpp(0, (int)__float_as_uint(x), 0x143, 0xc, 0xf, true)); x += t;
    return __uint_as_float((unsigned)__builtin_amdgcn_readlane((int)__float_as_uint(x), 63));
}

// ---------------- Kernel 1: coords = x@W_s + b_s ; feats = x@W_f + b_f ----------------
__global__ __launch_bounds__(256) void precompute_kernel(
    const float* __restrict__ x, const float* __restrict__ Ws, const float* __restrict__ bs,
    const float* __restrict__ Wf, const float* __restrict__ bf,
    float* __restrict__ coords, float* __restrict__ feats)
{
    int row = blockIdx.x * 256 + threadIdx.x;   // 0 .. B*N-1
    if (row >= BB * NN) return;

    const float4* x4 = (const float4*)(x + (size_t)row * FF);
    float c0 = bs[0], c1 = bs[1], c2 = bs[2], c3 = bs[3];
    float f[PP];
    #pragma unroll
    for (int c = 0; c < PP; c++) f[c] = bf[c];

    #pragma unroll
    for (int k4 = 0; k4 < FF / 4; k4++) {
        float4 xv = x4[k4];
        float xs[4] = {xv.x, xv.y, xv.z, xv.w};
        #pragma unroll
        for (int r = 0; r < 4; r++) {
            int k = k4 * 4 + r;
            float xk = xs[r];
            c0 = fmaf(xk, Ws[k * SS + 0], c0);
            c1 = fmaf(xk, Ws[k * SS + 1], c1);
            c2 = fmaf(xk, Ws[k * SS + 2], c2);
            c3 = fmaf(xk, Ws[k * SS + 3], c3);
            #pragma unroll
            for (int c = 0; c < PP; c++) f[c] = fmaf(xk, Wf[k * PP + c], f[c]);
        }
    }
    float4* cp = (float4*)(coords + (size_t)row * SS);
    *cp = make_float4(c0, c1, c2, c3);
    float* fo = feats + (size_t)row * PP;
    #pragma unroll
    for (int c = 0; c < PP; c++) fo[c] = f[c];
}

// ---------------- Kernel 2: wave-per-query kNN + aggregate + fused output matvec/tanh ----------------
// (128,4) -> 8 waves/EU budget. All 32 d2 in VGPRs. Dual-threshold bisection with DPP sums;
// DPP inclusive scan for the collect compaction (no ds_permute chains); tie-rank fast path.
__global__ __launch_bounds__(128, 4) void knn_out_kernel(
    const float* __restrict__ coords, const float* __restrict__ feats,
    const float* __restrict__ x, const float* __restrict__ Wo, const float* __restrict__ bo,
    const int* __restrict__ nnbr, float* __restrict__ out)
{
    const int lane = threadIdx.x & 63;
    const int w    = threadIdx.x >> 6;
    const int q    = blockIdx.x * 2 + w;       // 0..32767
    const int b    = q >> 11;
    const int i    = q & (NN - 1);

    int K = *nnbr; K = K < 2 ? 2 : (K > 64 ? 64 : K);

    __shared__ int   isel[2][64];
    __shared__ float wsel[2][64];
    __shared__ unsigned long long candk[2][64];   // (d2bits<<32)|j packed keys
    __shared__ __align__(16) float urow[2][112];  // [x | max | mean], 108 used

    const float4* cb = (const float4*)(coords + (size_t)b * NN * SS);
    float4 qv = cb[i];
    const float qx = readfirstlane_f32(qv.x);
    const float qy = readfirstlane_f32(qv.y);
    const float qz = readfirstlane_f32(qv.z);
    const float qw = readfirstlane_f32(qv.w);

    // ---- distances: all 2048 kept in 32 VGPRs/lane; track per-lane min ----
    float d2r[NREG];
    float lmin = INFINITY;
    #pragma unroll 4
    for (int r = 0; r < NREG; r++) {
        float4 c = cb[r * 64 + lane];
        float d0 = qx - c.x, d1 = qy - c.y, d2 = qz - c.z, d3 = qw - c.w;
        float v = d0 * d0 + d1 * d1 + d2 * d2 + d3 * d3;
        d2r[r] = v;
        lmin = fminf(lmin, v);
    }
    // stage x row for the epilogue (coalesced 256B per wave)
    urow[w][lane] = x[((size_t)b * NN + i) * FF + lane];
    __builtin_amdgcn_wave_barrier();

    // ---- first-probe estimator: mean of per-lane minima ~ K/N quantile (DPP sum) ----
    float t0 = wave_fsum_dpp(lmin) * (1.0f / 64.0f);

    // ---- dual-threshold bisection: invariant cnt_lt(lo) < K <= cnt_lt(hi) ----
    unsigned loU = 0u, hiU = 0x7F800000u;   // [0, +inf)
    int cLo = 0, cHi = NN;
    int laneLo = 0, laneHi = NREG;          // per-lane counts at loU / hiU
    float tPrev = t0; int cPrev = -1;
    int probes = 0;
    while (cHi - cLo > 64 && hiU - loU > 1u && probes < 20) {
        unsigned tAU = 0u, tBU = 0u;
        bool fell = false;
        if (probes == 0) {
            if (t0 > 0.f) { tAU = __float_as_uint(t0 * 0.80f); tBU = __float_as_uint(t0 * 1.30f); }
            else fell = true;
        } else if (cPrev > 0) {
            float g = tPrev * __fsqrt_rn((float)K / (float)cPrev);
            tAU = __float_as_uint(g * 0.88f); tBU = __float_as_uint(g * 1.18f);
        } else if (cPrev == 0) {
            tAU = __float_as_uint(tPrev * 3.0f); tBU = __float_as_uint(tPrev * 9.0f);
        } else fell = true;
        unsigned span = hiU - loU;
        if (fell || !(tAU > loU && tAU < hiU)) tAU = loU + span / 3u;
        if (tAU <= loU) tAU = loU + 1u;
        if (tAU >= hiU) tAU = hiU - 1u;
        if (fell || !(tBU >= tAU && tBU < hiU)) tBU = tAU + (hiU - tAU) / 2u;
        if (tBU < tAU) tBU = tAU;
        if (tBU >= hiU) tBU = hiU - 1u;

        float tA = __uint_as_float(tAU), tB = __uint_as_float(tBU);
        int clA = 0, clB = 0;
        #pragma unroll
        for (int r = 0; r < NREG; r++) {
            clA += (d2r[r] < tA) ? 1 : 0;
            clB += (d2r[r] < tB) ? 1 : 0;
        }
        int tot = wave_sum_dpp(clA | (clB << 16));   // sums fit 16 bits each (<= 2048)
        int cA = tot & 0xFFFF, cB = tot >> 16;

        if (cA >= K) { hiU = tAU; cHi = cA; laneHi = clA; }
        else {
            loU = tAU; cLo = cA; laneLo = clA;
            if (cB >= K) { hiU = tBU; cHi = cB; laneHi = clB; }
            else         { loU = tBU; cLo = cB; laneLo = clB; }
        }
        // anchor for the power-law guess: nonzero count closest to K
        int dA = cA > K ? cA - K : K - cA;
        int dB = cB > K ? cB - K : K - cB;
        if (cA > 0 && dA <= dB) { tPrev = tA; cPrev = cA; }
        else                    { tPrev = tB; cPrev = cB; }
        probes++;
    }

    const float lo = __uint_as_float(loU);
    const float hi = __uint_as_float(hiU);
    const int  need = K - cLo;              // in [1, K]; window holds >= need values

    // ---- collect: counts known per lane; DPP scan -> sequential writes ----
    int c1 = laneLo;                        // # of my elems with v < lo, minus self if below
    int c2 = laneHi - laneLo;               // # of my elems in [lo, hi)
    if (lane == (i & 63) && loU > 0u) c1 -= 1;   // self d2=0 < lo counted in laneLo
    int pk = c1 | (c2 << 16);
    int inc = wave_scan_dpp(pk);
    int excl = inc - pk;
    int tot  = __builtin_amdgcn_readlane(inc, 63);
    int b1 = excl & 0xFFFF;            // per-lane write base, below-window
    int b2 = excl >> 16;               // per-lane write base, candidates
    const int nbelow = tot & 0xFFFF;   // <= K-1
    int ecand = tot >> 16; if (ecand > 64) ecand = 64;
    #pragma unroll
    for (int r = 0; r < NREG; r++) {
        float v = d2r[r];
        int j = r * 64 + lane;
        if ((v < lo) & (j != i)) { isel[w][b1] = j; wsel[w][b1] = v; b1++; }
        else if ((v >= lo) & (v < hi)) { if (b2 < 64) candk[w][b2] = ((unsigned long long)__float_as_uint(v) << 32) | (unsigned)j; b2++; }
    }
    __builtin_amdgcn_wave_barrier();

    // ---- append `need` smallest candidates (value,index), skipping self ----
    int nsel;
    if (ecand == need && loU > 0u) {
        // fast path: window exactly fills remaining slots; self is below lo (excluded)
        if (lane < ecand) {
            int slot = nbelow + lane;
            if (slot < 64) {
                unsigned long long k2 = candk[w][lane];
                isel[w][slot] = (int)(k2 & 0xFFFFFFFFull);
                wsel[w][slot] = __uint_as_float((unsigned)(k2 >> 32));
            }
        }
        nsel = nbelow + ecand;
        if (nsel > 64) nsel = 64;
    } else {
        unsigned long long mykey = ~0ull;
        if (lane < ecand) mykey = candk[w][lane];
        int mr = 0;
        for (int u = 0; u < ecand; u++) {        // ds_read_b64 broadcast, conflict-free
            unsigned long long k2 = candk[w][u];
            mr += (k2 < mykey) ? 1 : 0;
        }
        int mj = (int)(mykey & 0xFFFFFFFFull);
        bool ps = (lane < ecand) & (mr < need) & (mj != i);
        unsigned long long ms = __ballot(ps);
        if (ps) {
            int slot = nbelow + __popcll(ms & ((1ull << lane) - 1ull));
            if (slot < 64) { isel[w][slot] = mj; wsel[w][slot] = __uint_as_float((unsigned)(mykey >> 32)); }
        }
        nsel = nbelow + __popcll(ms);
        if (nsel > 64) nsel = 64;                // expect K-1 = 39
    }
    __builtin_amdgcn_wave_barrier();
    if (lane < nsel) wsel[w][lane] = __expf(-wsel[w][lane]);
    __builtin_amdgcn_wave_barrier();

    // ---- weighted max / mean: lanes 0-21 do even m, lanes 32-53 odd m ----
    const float* fb = feats + (size_t)b * NN * PP;
    int g = lane >> 5, c = lane & 31;
    float mx = -INFINITY, sm = 0.f;
    if (c < PP) {
        #pragma unroll 4
        for (int m = g; m < nsel; m += 2) {
            int j = isel[w][m]; float wt = wsel[w][m];
            float f = fb[(size_t)j * PP + c];
            float wf = wt * f;
            mx = fmaxf(mx, wf); sm += wf;
        }
    }
    float mx2 = __shfl_xor(mx, 32, 64);
    float sm2 = __shfl_xor(sm, 32, 64);
    mx = fmaxf(mx, mx2); sm += sm2;
    if (g == 0 && c < PP) {
        urow[w][FF + c]      = mx;
        urow[w][FF + PP + c] = sm / (float)(K - 1);
    }
    __builtin_amdgcn_wave_barrier();

    // ---- fused epilogue: out[q][o] = tanh(urow . Wo[:,o] + bo[o]), lanes 0-41 ----
    // original Wo layout [108][42]: lane o reads Wo[k*42+o] -> coalesced across lanes.
    // 4 independent accumulator chains for ILP.
    if (lane < OO) {
        float a0 = bo[lane], a1 = 0.f, a2 = 0.f, a3 = 0.f;
        const float* wo = Wo + lane;
        #pragma unroll
        for (int k4 = 0; k4 < FPDIM / 4; k4++) {
            float4 u = *((const float4*)&urow[w][k4 * 4]);   // ds_read_b128 broadcast
            a0 = fmaf(u.x, wo[(k4 * 4 + 0) * OO], a0);
            a1 = fmaf(u.y, wo[(k4 * 4 + 1) * OO], a1);
            a2 = fmaf(u.z, wo[(k4 * 4 + 2) * OO], a2);
            a3 = fmaf(u.w, wo[(k4 * 4 + 3) * OO], a3);
        }
        float acc = (a0 + a1) + (a2 + a3);
        float a = acc < -12.f ? -12.f : (acc > 12.f ? 12.f : acc);
        float e2 = __expf(2.f * a);
        out[(size_t)q * OO + lane] = (e2 - 1.f) / (e2 + 1.f);
    }
}

extern "C" void kernel_launch(void* const* d_in, const int* in_sizes, int n_in,
                              void* d_out, int out_size, void* d_ws, size_t ws_size,
                              hipStream_t stream) {
    const float* x  = (const float*)d_in[0];
    const float* Ws = (const float*)d_in[1];
    const float* bs = (const float*)d_in[2];
    const float* Wf = (const float*)d_in[3];
    const float* bf = (const float*)d_in[4];
    const float* Wo = (const float*)d_in[5];
    const float* bo = (const float*)d_in[6];
    const int*   nn = (const int*)d_in[7];
    float* out = (float*)d_out;

    float* coords = (float*)d_ws;                              // 16*2048*4  = 512 KB
    float* feats  = coords + (size_t)BB * NN * SS;             // 16*2048*22 = 2.75 MB

    precompute_kernel<<<(BB * NN) / 256, 256, 0, stream>>>(x, Ws, bs, Wf, bf, coords, feats);
    knn_out_kernel<<<(BB * NN) / 2, 128, 0, stream>>>(coords, feats, x, Wo, bo, nn, out);
}